// Round 16
// baseline (46.838 us; speedup 1.0000x reference)
//
#include <hip/hip_runtime.h>
#include <hip/hip_bf16.h>

#define B_  4
#define S_  512
#define D_  512
#define H_  8
#define HD_ 64
#define F_  5
#define NROW (B_*S_)     // 2048
#define BHS  (B_*H_*S_)  // 16384
#define EPS_ 1e-8f

typedef __attribute__((ext_vector_type(8))) short bf16x8;
typedef __attribute__((ext_vector_type(4))) float f32x4;

static __device__ __forceinline__ short f2bf(float f) {
    __hip_bfloat16 h = __float2bfloat16(f);
    return *reinterpret_cast<short*>(&h);
}

// async global->LDS, 16B per lane; dest = ldsbase + lane*16 (wave-linear)
#define GLOAD16(ldsp, gp) \
    __builtin_amdgcn_global_load_lds( \
        (const __attribute__((address_space(1))) unsigned int*)(gp), \
        (__attribute__((address_space(3))) unsigned int*)(ldsp), 16, 0, 0)

// Bank-conflict swizzle (rule #21, verified R12): LDS dest linear, SOURCE
// slot pre-permuted (slot ^= row&7), READ XOR'd with (row&7)<<4.
#define SWZR(byte, row) ((byte) ^ (((row) & 7) << 4))

// ---------------------------------------------------------------------------
// C1: merged conversions (R14 body).
// ---------------------------------------------------------------------------
__global__ __launch_bounds__(256) void convert_fused(
    const float* __restrict__ x,
    const float* __restrict__ Wq, const float* __restrict__ Wk,
    const float* __restrict__ Wv, const float* __restrict__ Wo,
    short* __restrict__ xb, short* __restrict__ WqkvT, short* __restrict__ WoT)
{
    const int bid = blockIdx.x;
    if (bid < 256) {
#pragma unroll
        for (int u = 0; u < 4; ++u) {
            int i = bid * 1024 + u * 256 + threadIdx.x;   // 262144 float4s
            f32x4 f = __builtin_nontemporal_load(
                reinterpret_cast<const f32x4*>(x) + i);
            short4 o;
            o.x = f2bf(f[0]); o.y = f2bf(f[1]); o.z = f2bf(f[2]); o.w = f2bf(f[3]);
            reinterpret_cast<short4*>(xb)[i] = o;
        }
        return;
    }
    const int wb = bid - 256;
    const int widx = wb >> 6;                  // 0..3
    const int tile = wb & 63;                  // 8x8 tiles of 64x64
    const int k0 = (tile >> 3) * 64, n0 = (tile & 7) * 64;
    const float* __restrict__ src = widx==0?Wq:(widx==1?Wk:(widx==2?Wv:Wo));
    short* __restrict__ dst = (widx < 3) ? WqkvT : WoT;
    const int drow0 = (widx < 3) ? widx * 512 : 0;

    __shared__ short T[64][72];
    const int t = threadIdx.x;
    const int r = t >> 2, qq = t & 3;
#pragma unroll
    for (int i = 0; i < 4; ++i) {
        f32x4 f = __builtin_nontemporal_load(
            reinterpret_cast<const f32x4*>(&src[(k0+r)*D_ + n0 + qq*16 + i*4]));
        T[r][qq*16+i*4+0] = f2bf(f[0]);
        T[r][qq*16+i*4+1] = f2bf(f[1]);
        T[r][qq*16+i*4+2] = f2bf(f[2]);
        T[r][qq*16+i*4+3] = f2bf(f[3]);
    }
    __syncthreads();
    const int c = t >> 2;                       // local n
#pragma unroll
    for (int i = 0; i < 4; ++i) {
        short4 o;
        o.x = T[qq*16+i*4+0][c];
        o.y = T[qq*16+i*4+1][c];
        o.z = T[qq*16+i*4+2][c];
        o.w = T[qq*16+i*4+3][c];
        *reinterpret_cast<short4*>(&dst[(size_t)(drow0+n0+c)*512 + k0 + qq*16 + i*4]) = o;
    }
}

// ---------------------------------------------------------------------------
// K1: QKV MFMA GEMM + fused membership/vT (R14 body: 64x64, BK=128,
// grid 768 = 3/CU, 32KB swizzled LDS).
// ---------------------------------------------------------------------------
__global__ __launch_bounds__(256) void qkv_mfma(
    const short* __restrict__ Ab, const short* __restrict__ BT,
    const float* __restrict__ bq, const float* __restrict__ bk,
    const float* __restrict__ bv,
    const float* __restrict__ gc, const float* __restrict__ gs,
    const float* __restrict__ gw,
    float* __restrict__ qm, float* __restrict__ km, short* __restrict__ vT)
{
    __shared__ short As[64*128];   // [row][kslot^swz] 16KB, 256B rows
    __shared__ short Bs[64*128];   // 16KB
    const int tid = threadIdx.x;
    const int wid = tid >> 6, lane = tid & 63;
    const int m0 = blockIdx.x * 64;
    const int n0 = blockIdx.y * 64;            // within 1536

    f32x4 acc[4] = {};
    const int rl4 = lane >> 4;                 // row within 4-row chunk

#pragma unroll
    for (int k0 = 0; k0 < 512; k0 += 128) {
#pragma unroll
        for (int i = 0; i < 4; ++i) {
            const int c = wid*4 + i;
            const int grow = c*4 + rl4;
            const int slot = (lane & 15) ^ (grow & 7);
            GLOAD16(&As[c*512], &Ab[(size_t)(m0 + grow)*512 + k0 + slot*8]);
            GLOAD16(&Bs[c*512], &BT[(size_t)(n0 + grow)*512 + k0 + slot*8]);
        }
        asm volatile("s_waitcnt vmcnt(0)" ::: "memory");
        __syncthreads();
#pragma unroll
        for (int ks = 0; ks < 4; ++ks) {
            const int ar = wid*16 + (lane & 15);
            const int abyte = ar*256 + ks*64 + (lane>>4)*16;
            const bf16x8 a = *reinterpret_cast<const bf16x8*>(
                reinterpret_cast<const char*>(As) + SWZR(abyte, ar));
#pragma unroll
            for (int f = 0; f < 4; ++f) {
                const int br = f*16 + (lane & 15);
                const int bbyte = br*256 + ks*64 + (lane>>4)*16;
                const bf16x8 b = *reinterpret_cast<const bf16x8*>(
                    reinterpret_cast<const char*>(Bs) + SWZR(bbyte, br));
                acc[f] = __builtin_amdgcn_mfma_f32_16x16x32_bf16(a, b, acc[f], 0, 0, 0);
            }
        }
        __syncthreads();
    }

    const int wsel = blockIdx.y >> 3;          // 0:q 1:k 2:v
    const int h = blockIdx.y & 7;              // head (64-col tile == head)
    const int b_ = m0 >> 9;
    const int bh = b_*H_ + h;
    const int hdl = lane & 15;
    const int srow0 = (m0 & 511) + wid*16 + (lane>>4)*4;

    if (wsel < 2) {
        // ---- fused Gaussian membership ----
        const float* __restrict__ bias = wsel==0 ? bq : bk;
        float* __restrict__ dst        = wsel==0 ? qm : km;
        float gcv[F_][4], isv[F_][4], bi4[4];
#pragma unroll
        for (int f = 0; f < F_; ++f)
#pragma unroll
            for (int j = 0; j < 4; ++j) {
                const int hd = j*16 + hdl;
                gcv[f][j] = gc[f*HD_ + hd];
                isv[f][j] = 1.0f / (gs[f*HD_ + hd] + EPS_);
            }
#pragma unroll
        for (int j = 0; j < 4; ++j) bi4[j] = bias[h*64 + j*16 + hdl];
        float gwv[F_];
#pragma unroll
        for (int f = 0; f < F_; ++f) gwv[f] = gw[f];

#pragma unroll
        for (int r = 0; r < 4; ++r) {
            float z[4];
#pragma unroll
            for (int j = 0; j < 4; ++j) z[j] = acc[j][r] + bi4[j];
            float p[F_];
#pragma unroll
            for (int f = 0; f < F_; ++f) {
                float t = 0.f;
#pragma unroll
                for (int j = 0; j < 4; ++j) {
                    const float nd = (z[j] - gcv[f][j]) * isv[f][j];
                    t = fmaf(nd*nd, -0.5f, t);
                }
                p[f] = t;
            }
#pragma unroll
            for (int off = 1; off < 16; off <<= 1)
#pragma unroll
                for (int f = 0; f < F_; ++f) p[f] += __shfl_xor(p[f], off, 64);
            if (hdl == 0) {
                const int s = srow0 + r;
                float* o = &dst[((size_t)bh*S_ + s)*F_];
#pragma unroll
                for (int f = 0; f < F_; ++f) o[f] = __expf(p[f]) * gwv[f];
            }
        }
    } else {
        // ---- fused V transpose: vT[bh][hd][s] bf16 ----
        float bi4[4];
#pragma unroll
        for (int j = 0; j < 4; ++j) bi4[j] = bv[h*64 + j*16 + hdl];
#pragma unroll
        for (int j = 0; j < 4; ++j) {
            short4 o;
            o.x = f2bf(acc[j][0] + bi4[j]);
            o.y = f2bf(acc[j][1] + bi4[j]);
            o.z = f2bf(acc[j][2] + bi4[j]);
            o.w = f2bf(acc[j][3] + bi4[j]);
            *reinterpret_cast<short4*>(
                &vT[((size_t)bh*HD_ + j*16 + hdl)*S_ + srow0]) = o;
        }
    }
}

// ---------------------------------------------------------------------------
// K2: fused scores + softmax + attn-write + PV MFMA.
// 16-row tiles: LDS 16.4KB -> 4 blocks/CU (was 2), grid 1024 = 4/CU exact.
// Doubled TLP to hide the serial shfl-reduce chains + attn-write drain.
// ---------------------------------------------------------------------------
__global__ __launch_bounds__(256) void scores_av(
    const float* __restrict__ qm, const float* __restrict__ km,
    const float* __restrict__ tw, const short* __restrict__ vT,
    float* __restrict__ attn, short* __restrict__ ctxb)
{
    __shared__ float qs[16*F_];            // 320B
    __shared__ short P[16*512];            // 16KB, [row][j] with byte^=(row&7)<<4
    const int s0 = blockIdx.x * 16;
    const int bh = blockIdx.y;
    const int tid = threadIdx.x, w = tid >> 6, lane = tid & 63;

    const float t0 = tw[0], t1 = tw[1], t2 = tw[2];
    const float mx3 = fmaxf(t0, fmaxf(t1, t2));
    const float e0 = __expf(t0-mx3), e1 = __expf(t1-mx3), e2 = __expf(t2-mx3);
    const float inv3 = 1.0f / (e0+e1+e2);
    const float w0 = e0*inv3, w1 = e1*inv3, w2 = e2*inv3;

    if (tid < 16*F_) qs[tid] = qm[((size_t)bh*S_ + s0)*F_ + tid];

    float krf[40];
    {
        const float4* kmp = reinterpret_cast<const float4*>(
            &km[(size_t)bh*S_*F_ + lane*40]);
#pragma unroll
        for (int u = 0; u < 10; ++u)
            reinterpret_cast<float4*>(krf)[u] = kmp[u];
    }
    __syncthreads();

    // --- score phase: 4 rows per wave, fully unrolled ---
#pragma unroll
    for (int rl = 0; rl < 4; ++rl) {
        const int i = w*4 + rl;                        // local row 0..15
        const float q0 = qs[i*F_+0], q1 = qs[i*F_+1], q2 = qs[i*F_+2],
                    q3 = qs[i*F_+3], q4 = qs[i*F_+4];
        float e[8], sum = 0.f;
#pragma unroll
        for (int jj = 0; jj < 8; ++jj) {
            const float *kk = &krf[jj*F_];
            float prod = q0*kk[0] + q1*kk[1] + q2*kk[2] + q3*kk[3] + q4*kk[4];
            float mn = fminf(q0,kk[0]) + fminf(q1,kk[1]) + fminf(q2,kk[2])
                     + fminf(q3,kk[3]) + fminf(q4,kk[4]);
            float lk = fmaxf(q0+kk[0]-1.f,0.f) + fmaxf(q1+kk[1]-1.f,0.f)
                     + fmaxf(q2+kk[2]-1.f,0.f) + fmaxf(q3+kk[3]-1.f,0.f)
                     + fmaxf(q4+kk[4]-1.f,0.f);
            e[jj] = __expf(w0*prod + w1*mn + w2*lk);
            sum += e[jj];
        }
#pragma unroll
        for (int off = 32; off > 0; off >>= 1) sum += __shfl_xor(sum, off, 64);
        const float invs = 1.0f / sum;

        float a[8];
#pragma unroll
        for (int jj = 0; jj < 8; ++jj) a[jj] = e[jj]*invs;
        float* arow = &attn[((size_t)(bh*S_ + s0 + i))*S_ + lane*8];
        f32x4 v0 = { a[0], a[1], a[2], a[3] };
        f32x4 v1 = { a[4], a[5], a[6], a[7] };
        __builtin_nontemporal_store(v0, reinterpret_cast<f32x4*>(arow));
        __builtin_nontemporal_store(v1, reinterpret_cast<f32x4*>(arow) + 1);
        bf16x8 pk;
#pragma unroll
        for (int jj = 0; jj < 8; ++jj) pk[jj] = f2bf(a[jj]);
        *reinterpret_cast<bf16x8*>(
            reinterpret_cast<char*>(P) + ((i*1024 + lane*16) ^ ((i&7)<<4))) = pk;
    }
    __syncthreads();

    // --- PV phase: wave w owns all 16 rows x hd quarter [w*16, w*16+16) ---
    const short* __restrict__ Vb = vT + (size_t)bh*HD_*S_;
    f32x4 acc = {};
    const int arow = lane & 15;                // local row
    const int asw  = (arow & 7) << 4;
#pragma unroll
    for (int ks = 0; ks < 16; ++ks) {
        const int abyte = arow*1024 + ks*64 + (lane>>4)*16;
        const bf16x8 a = *reinterpret_cast<const bf16x8*>(
            reinterpret_cast<const char*>(P) + (abyte ^ asw));
        const bf16x8 b = *reinterpret_cast<const bf16x8*>(
            &Vb[(size_t)(w*16 + (lane & 15))*S_ + ks*32 + (lane>>4)*8]);
        acc = __builtin_amdgcn_mfma_f32_16x16x32_bf16(a, b, acc, 0, 0, 0);
    }
    const int b_ = bh >> 3, h = bh & 7;
#pragma unroll
    for (int r = 0; r < 4; ++r) {
        const int s = s0 + (lane>>4)*4 + r;
        ctxb[((size_t)(b_*S_ + s))*D_ + h*HD_ + w*16 + (lane & 15)]
            = f2bf(acc[r]);
    }
}

// ---------------------------------------------------------------------------
// K3: out = ctxb @ WoT + bo (R14 body: 32x64, BK=128, grid 512 = 2/CU).
// ---------------------------------------------------------------------------
__global__ __launch_bounds__(256) void out_mfma(
    const short* __restrict__ ctxb, const short* __restrict__ WoT,
    const float* __restrict__ bo, float* __restrict__ out)
{
    const int m0 = blockIdx.x * 32;
    const int n0 = blockIdx.y * 64;

    __shared__ short As[32*128];  // 8KB  (8 chunks of 4 rows)
    __shared__ short Bs[64*128];  // 16KB (16 chunks)
    const int tid = threadIdx.x;
    const int wid = tid >> 6, lane = tid & 63;

    f32x4 acc[2] = {};
    const int rl4 = lane >> 4;

#pragma unroll
    for (int k0 = 0; k0 < D_; k0 += 128) {
#pragma unroll
        for (int i = 0; i < 2; ++i) {
            const int c = wid*2 + i;
            const int grow = c*4 + rl4;
            const int slot = (lane & 15) ^ (grow & 7);
            GLOAD16(&As[c*512], &ctxb[(size_t)(m0 + grow)*D_ + k0 + slot*8]);
        }
#pragma unroll
        for (int i = 0; i < 4; ++i) {
            const int c = wid*4 + i;
            const int grow = c*4 + rl4;
            const int slot = (lane & 15) ^ (grow & 7);
            GLOAD16(&Bs[c*512], &WoT[(size_t)(n0 + grow)*D_ + k0 + slot*8]);
        }
        asm volatile("s_waitcnt vmcnt(0)" ::: "memory");
        __syncthreads();
#pragma unroll
        for (int ks = 0; ks < 4; ++ks) {
            const int br = wid*16 + (lane & 15);
            const int bbyte = br*256 + ks*64 + (lane>>4)*16;
            const bf16x8 b = *reinterpret_cast<const bf16x8*>(
                reinterpret_cast<const char*>(Bs) + SWZR(bbyte, br));
#pragma unroll
            for (int i = 0; i < 2; ++i) {
                const int ar = i*16 + (lane & 15);
                const int abyte = ar*256 + ks*64 + (lane>>4)*16;
                const bf16x8 a = *reinterpret_cast<const bf16x8*>(
                    reinterpret_cast<const char*>(As) + SWZR(abyte, ar));
                acc[i] = __builtin_amdgcn_mfma_f32_16x16x32_bf16(a, b, acc[i], 0, 0, 0);
            }
        }
        __syncthreads();
    }
#pragma unroll
    for (int i = 0; i < 2; ++i)
#pragma unroll
        for (int r = 0; r < 4; ++r) {
            const int m = m0 + i*16 + (lane>>4)*4 + r;
            const int n = n0 + wid*16 + (lane & 15);
            __builtin_nontemporal_store(acc[i][r], &out[(size_t)m*D_ + n]);
        }
}

// ---------------------------------------------------------------------------
extern "C" void kernel_launch(void* const* d_in, const int* in_sizes, int n_in,
                              void* d_out, int out_size, void* d_ws, size_t ws_size,
                              hipStream_t stream)
{
    const float* x  = (const float*)d_in[0];
    const float* Wq = (const float*)d_in[1];
    const float* bq = (const float*)d_in[2];
    const float* Wk = (const float*)d_in[3];
    const float* bk = (const float*)d_in[4];
    const float* Wv = (const float*)d_in[5];
    const float* bv = (const float*)d_in[6];
    const float* Wo = (const float*)d_in[7];
    const float* bo = (const float*)d_in[8];
    const float* gc = (const float*)d_in[9];
    const float* gs = (const float*)d_in[10];
    const float* gw = (const float*)d_in[11];
    const float* tw = (const float*)d_in[12];

    short* xb    = (short*)d_ws;                      // 1,048,576 bf16
    short* WqkvT = xb + 1048576;                      //   786,432 bf16
    short* WoT   = WqkvT + 786432;                    //   262,144 bf16
    short* vT    = WoT + 262144;                      // 1,048,576 bf16
    short* ctxb  = vT + 1048576;                      // 1,048,576 bf16
    float* qm    = (float*)(ctxb + 1048576);          //    81,920 f32
    float* km    = qm + 81920;                        //    81,920 f32

    float* out0 = (float*)d_out;                      // (B,S,D)
    float* attn = out0 + (size_t)B_*S_*D_;            // (B,H,S,S)

    convert_fused<<<512, 256, 0, stream>>>(x, Wq, Wk, Wv, Wo, xb, WqkvT, WoT);
    qkv_mfma<<<dim3(NROW/64, 1536/64), 256, 0, stream>>>(
        xb, WqkvT, bq, bk, bv, gc, gs, gw, qm, km, vT);
    scores_av<<<dim3(S_/16, B_*H_), 256, 0, stream>>>(qm, km, tw, vT, attn, ctxb);
    out_mfma<<<dim3(NROW/32, D_/64), 256, 0, stream>>>(ctxb, WoT, bo, out0);
}

// Round 17
// 45.404 us; speedup vs baseline: 1.0316x; 1.0316x over previous
//
#include <hip/hip_runtime.h>
#include <hip/hip_bf16.h>

#define B_  4
#define S_  512
#define D_  512
#define H_  8
#define HD_ 64
#define F_  5
#define NROW (B_*S_)     // 2048
#define BHS  (B_*H_*S_)  // 16384
#define EPS_ 1e-8f

typedef __attribute__((ext_vector_type(8))) short bf16x8;
typedef __attribute__((ext_vector_type(4))) float f32x4;

static __device__ __forceinline__ short f2bf(float f) {
    __hip_bfloat16 h = __float2bfloat16(f);
    return *reinterpret_cast<short*>(&h);
}

// async global->LDS, 16B per lane; dest = ldsbase + lane*16 (wave-linear)
#define GLOAD16(ldsp, gp) \
    __builtin_amdgcn_global_load_lds( \
        (const __attribute__((address_space(1))) unsigned int*)(gp), \
        (__attribute__((address_space(3))) unsigned int*)(ldsp), 16, 0, 0)

// Bank-conflict swizzle (rule #21, verified R12): LDS dest linear, SOURCE
// slot pre-permuted (slot ^= row&7), READ XOR'd with (row&7)<<4.
#define SWZR(byte, row) ((byte) ^ (((row) & 7) << 4))

// ---------------------------------------------------------------------------
// C1: merged conversions.
// ---------------------------------------------------------------------------
__global__ __launch_bounds__(256) void convert_fused(
    const float* __restrict__ x,
    const float* __restrict__ Wq, const float* __restrict__ Wk,
    const float* __restrict__ Wv, const float* __restrict__ Wo,
    short* __restrict__ xb, short* __restrict__ WqkvT, short* __restrict__ WoT)
{
    const int bid = blockIdx.x;
    if (bid < 256) {
#pragma unroll
        for (int u = 0; u < 4; ++u) {
            int i = bid * 1024 + u * 256 + threadIdx.x;   // 262144 float4s
            float4 f = reinterpret_cast<const float4*>(x)[i];
            short4 o;
            o.x = f2bf(f.x); o.y = f2bf(f.y); o.z = f2bf(f.z); o.w = f2bf(f.w);
            reinterpret_cast<short4*>(xb)[i] = o;
        }
        return;
    }
    const int wb = bid - 256;
    const int widx = wb >> 6;                  // 0..3
    const int tile = wb & 63;                  // 8x8 tiles of 64x64
    const int k0 = (tile >> 3) * 64, n0 = (tile & 7) * 64;
    const float* __restrict__ src = widx==0?Wq:(widx==1?Wk:(widx==2?Wv:Wo));
    short* __restrict__ dst = (widx < 3) ? WqkvT : WoT;
    const int drow0 = (widx < 3) ? widx * 512 : 0;

    __shared__ short T[64][72];
    const int t = threadIdx.x;
    const int r = t >> 2, qq = t & 3;
#pragma unroll
    for (int i = 0; i < 4; ++i) {
        float4 f = *reinterpret_cast<const float4*>(&src[(k0+r)*D_ + n0 + qq*16 + i*4]);
        T[r][qq*16+i*4+0] = f2bf(f.x);
        T[r][qq*16+i*4+1] = f2bf(f.y);
        T[r][qq*16+i*4+2] = f2bf(f.z);
        T[r][qq*16+i*4+3] = f2bf(f.w);
    }
    __syncthreads();
    const int c = t >> 2;                       // local n
#pragma unroll
    for (int i = 0; i < 4; ++i) {
        short4 o;
        o.x = T[qq*16+i*4+0][c];
        o.y = T[qq*16+i*4+1][c];
        o.z = T[qq*16+i*4+2][c];
        o.w = T[qq*16+i*4+3][c];
        *reinterpret_cast<short4*>(&dst[(size_t)(drow0+n0+c)*512 + k0 + qq*16 + i*4]) = o;
    }
}

// ---------------------------------------------------------------------------
// K1: QKV MFMA GEMM + fused membership/vT.  64x64 tile, BK=128, grid 768 =
// 3/CU, 32KB swizzled LDS.
// ---------------------------------------------------------------------------
__global__ __launch_bounds__(256) void qkv_mfma(
    const short* __restrict__ Ab, const short* __restrict__ BT,
    const float* __restrict__ bq, const float* __restrict__ bk,
    const float* __restrict__ bv,
    const float* __restrict__ gc, const float* __restrict__ gs,
    const float* __restrict__ gw,
    float* __restrict__ qm, float* __restrict__ km, short* __restrict__ vT)
{
    __shared__ short As[64*128];   // [row][kslot^swz] 16KB, 256B rows
    __shared__ short Bs[64*128];   // 16KB
    const int tid = threadIdx.x;
    const int wid = tid >> 6, lane = tid & 63;
    const int m0 = blockIdx.x * 64;
    const int n0 = blockIdx.y * 64;            // within 1536

    f32x4 acc[4] = {};
    const int rl4 = lane >> 4;                 // row within 4-row chunk

    for (int k0 = 0; k0 < 512; k0 += 128) {
        // 16 chunks each of A,B (1KB = 4 rows x 256B); 4 per wave.
#pragma unroll
        for (int i = 0; i < 4; ++i) {
            const int c = wid*4 + i;
            const int grow = c*4 + rl4;
            const int slot = (lane & 15) ^ (grow & 7);
            GLOAD16(&As[c*512], &Ab[(size_t)(m0 + grow)*512 + k0 + slot*8]);
            GLOAD16(&Bs[c*512], &BT[(size_t)(n0 + grow)*512 + k0 + slot*8]);
        }
        asm volatile("s_waitcnt vmcnt(0)" ::: "memory");
        __syncthreads();
#pragma unroll
        for (int ks = 0; ks < 4; ++ks) {
            const int ar = wid*16 + (lane & 15);
            const int abyte = ar*256 + ks*64 + (lane>>4)*16;
            const bf16x8 a = *reinterpret_cast<const bf16x8*>(
                reinterpret_cast<const char*>(As) + SWZR(abyte, ar));
#pragma unroll
            for (int f = 0; f < 4; ++f) {
                const int br = f*16 + (lane & 15);
                const int bbyte = br*256 + ks*64 + (lane>>4)*16;
                const bf16x8 b = *reinterpret_cast<const bf16x8*>(
                    reinterpret_cast<const char*>(Bs) + SWZR(bbyte, br));
                acc[f] = __builtin_amdgcn_mfma_f32_16x16x32_bf16(a, b, acc[f], 0, 0, 0);
            }
        }
        __syncthreads();
    }

    const int wsel = blockIdx.y >> 3;          // 0:q 1:k 2:v
    const int h = blockIdx.y & 7;              // head (64-col tile == head)
    const int b_ = m0 >> 9;
    const int bh = b_*H_ + h;
    const int hdl = lane & 15;
    const int srow0 = (m0 & 511) + wid*16 + (lane>>4)*4;

    if (wsel < 2) {
        // ---- fused Gaussian membership ----
        const float* __restrict__ bias = wsel==0 ? bq : bk;
        float* __restrict__ dst        = wsel==0 ? qm : km;
        float gcv[F_][4], isv[F_][4], bi4[4];
#pragma unroll
        for (int f = 0; f < F_; ++f)
#pragma unroll
            for (int j = 0; j < 4; ++j) {
                const int hd = j*16 + hdl;
                gcv[f][j] = gc[f*HD_ + hd];
                isv[f][j] = 1.0f / (gs[f*HD_ + hd] + EPS_);
            }
#pragma unroll
        for (int j = 0; j < 4; ++j) bi4[j] = bias[h*64 + j*16 + hdl];
        float gwv[F_];
#pragma unroll
        for (int f = 0; f < F_; ++f) gwv[f] = gw[f];

#pragma unroll
        for (int r = 0; r < 4; ++r) {
            float z[4];
#pragma unroll
            for (int j = 0; j < 4; ++j) z[j] = acc[j][r] + bi4[j];
            float p[F_];
#pragma unroll
            for (int f = 0; f < F_; ++f) {
                float t = 0.f;
#pragma unroll
                for (int j = 0; j < 4; ++j) {
                    const float nd = (z[j] - gcv[f][j]) * isv[f][j];
                    t = fmaf(nd*nd, -0.5f, t);
                }
                p[f] = t;
            }
#pragma unroll
            for (int off = 1; off < 16; off <<= 1)
#pragma unroll
                for (int f = 0; f < F_; ++f) p[f] += __shfl_xor(p[f], off, 64);
            if (hdl == 0) {
                const int s = srow0 + r;
                float* o = &dst[((size_t)bh*S_ + s)*F_];
#pragma unroll
                for (int f = 0; f < F_; ++f) o[f] = __expf(p[f]) * gwv[f];
            }
        }
    } else {
        // ---- fused V transpose: vT[bh][hd][s] bf16 ----
        float bi4[4];
#pragma unroll
        for (int j = 0; j < 4; ++j) bi4[j] = bv[h*64 + j*16 + hdl];
#pragma unroll
        for (int j = 0; j < 4; ++j) {
            short4 o;
            o.x = f2bf(acc[j][0] + bi4[j]);
            o.y = f2bf(acc[j][1] + bi4[j]);
            o.z = f2bf(acc[j][2] + bi4[j]);
            o.w = f2bf(acc[j][3] + bi4[j]);
            *reinterpret_cast<short4*>(
                &vT[((size_t)bh*HD_ + j*16 + hdl)*S_ + srow0]) = o;
        }
    }
}

// ---------------------------------------------------------------------------
// K2: fused scores + softmax + attn-write + PV MFMA (32-row tiles, the best
// measured variant).
// ---------------------------------------------------------------------------
__global__ __launch_bounds__(256) void scores_av(
    const float* __restrict__ qm, const float* __restrict__ km,
    const float* __restrict__ tw, const short* __restrict__ vT,
    float* __restrict__ attn, short* __restrict__ ctxb)
{
    __shared__ float qs[32*F_];            // 640B
    __shared__ short P[32*512];            // 32KB, [row][j] with byte^=(row&7)<<4
    const int s0 = blockIdx.x * 32;
    const int bh = blockIdx.y;
    const int tid = threadIdx.x, w = tid >> 6, lane = tid & 63;

    const float t0 = tw[0], t1 = tw[1], t2 = tw[2];
    const float mx3 = fmaxf(t0, fmaxf(t1, t2));
    const float e0 = __expf(t0-mx3), e1 = __expf(t1-mx3), e2 = __expf(t2-mx3);
    const float inv3 = 1.0f / (e0+e1+e2);
    const float w0 = e0*inv3, w1 = e1*inv3, w2 = e2*inv3;

    if (tid < 32*F_) qs[tid] = qm[((size_t)bh*S_ + s0)*F_ + tid];

    float krf[40];
    {
        const float4* kmp = reinterpret_cast<const float4*>(
            &km[(size_t)bh*S_*F_ + lane*40]);
#pragma unroll
        for (int u = 0; u < 10; ++u)
            reinterpret_cast<float4*>(krf)[u] = kmp[u];
    }
    __syncthreads();

#pragma unroll 2
    for (int rl = 0; rl < 8; ++rl) {
        const int i = w*8 + rl;                        // local row 0..31
        const float q0 = qs[i*F_+0], q1 = qs[i*F_+1], q2 = qs[i*F_+2],
                    q3 = qs[i*F_+3], q4 = qs[i*F_+4];
        float e[8], sum = 0.f;
#pragma unroll
        for (int jj = 0; jj < 8; ++jj) {
            const float *kk = &krf[jj*F_];
            float prod = q0*kk[0] + q1*kk[1] + q2*kk[2] + q3*kk[3] + q4*kk[4];
            float mn = fminf(q0,kk[0]) + fminf(q1,kk[1]) + fminf(q2,kk[2])
                     + fminf(q3,kk[3]) + fminf(q4,kk[4]);
            float lk = fmaxf(q0+kk[0]-1.f,0.f) + fmaxf(q1+kk[1]-1.f,0.f)
                     + fmaxf(q2+kk[2]-1.f,0.f) + fmaxf(q3+kk[3]-1.f,0.f)
                     + fmaxf(q4+kk[4]-1.f,0.f);
            e[jj] = __expf(w0*prod + w1*mn + w2*lk);
            sum += e[jj];
        }
#pragma unroll
        for (int off = 32; off > 0; off >>= 1) sum += __shfl_xor(sum, off, 64);
        const float invs = 1.0f / sum;

        float a[8];
#pragma unroll
        for (int jj = 0; jj < 8; ++jj) a[jj] = e[jj]*invs;
        float* arow = &attn[((size_t)(bh*S_ + s0 + i))*S_ + lane*8];
        f32x4 v0 = { a[0], a[1], a[2], a[3] };
        f32x4 v1 = { a[4], a[5], a[6], a[7] };
        __builtin_nontemporal_store(v0, reinterpret_cast<f32x4*>(arow));
        __builtin_nontemporal_store(v1, reinterpret_cast<f32x4*>(arow) + 1);
        bf16x8 pk;
#pragma unroll
        for (int jj = 0; jj < 8; ++jj) pk[jj] = f2bf(a[jj]);
        *reinterpret_cast<bf16x8*>(
            reinterpret_cast<char*>(P) + ((i*1024 + lane*16) ^ ((i&7)<<4))) = pk;
    }
    __syncthreads();

    // --- PV phase: wave = (16-row half h0) x (32-hd half f0*16) ---
    const short* __restrict__ Vb = vT + (size_t)bh*HD_*S_;
    const int h0 = (w & 1) * 16;
    const int f0 = (w >> 1) * 2;
    f32x4 acc[2] = {};
    const int arow = h0 + (lane & 15);
    const int asw  = (arow & 7) << 4;
#pragma unroll
    for (int ks = 0; ks < 16; ++ks) {
        const int abyte = arow*1024 + ks*64 + (lane>>4)*16;
        const bf16x8 a = *reinterpret_cast<const bf16x8*>(
            reinterpret_cast<const char*>(P) + (abyte ^ asw));
#pragma unroll
        for (int ff = 0; ff < 2; ++ff) {
            const bf16x8 b = *reinterpret_cast<const bf16x8*>(
                &Vb[(size_t)((f0+ff)*16 + (lane & 15))*S_ + ks*32 + (lane>>4)*8]);
            acc[ff] = __builtin_amdgcn_mfma_f32_16x16x32_bf16(a, b, acc[ff], 0, 0, 0);
        }
    }
    const int b_ = bh >> 3, h = bh & 7;
#pragma unroll
    for (int ff = 0; ff < 2; ++ff)
#pragma unroll
        for (int r = 0; r < 4; ++r) {
            const int s = s0 + h0 + (lane>>4)*4 + r;
            ctxb[((size_t)(b_*S_ + s))*D_ + h*HD_ + (f0+ff)*16 + (lane & 15)]
                = f2bf(acc[ff][r]);
        }
}

// ---------------------------------------------------------------------------
// K3: out = ctxb @ WoT + bo.  32x64 tile, BK=128, grid 512 = 2/CU, swizzled.
// ---------------------------------------------------------------------------
__global__ __launch_bounds__(256) void out_mfma(
    const short* __restrict__ ctxb, const short* __restrict__ WoT,
    const float* __restrict__ bo, float* __restrict__ out)
{
    const int m0 = blockIdx.x * 32;
    const int n0 = blockIdx.y * 64;

    __shared__ short As[32*128];  // 8KB  (8 chunks of 4 rows)
    __shared__ short Bs[64*128];  // 16KB (16 chunks)
    const int tid = threadIdx.x;
    const int wid = tid >> 6, lane = tid & 63;

    f32x4 acc[2] = {};
    const int rl4 = lane >> 4;

    for (int k0 = 0; k0 < D_; k0 += 128) {
#pragma unroll
        for (int i = 0; i < 2; ++i) {
            const int c = wid*2 + i;
            const int grow = c*4 + rl4;
            const int slot = (lane & 15) ^ (grow & 7);
            GLOAD16(&As[c*512], &ctxb[(size_t)(m0 + grow)*D_ + k0 + slot*8]);
        }
#pragma unroll
        for (int i = 0; i < 4; ++i) {
            const int c = wid*4 + i;
            const int grow = c*4 + rl4;
            const int slot = (lane & 15) ^ (grow & 7);
            GLOAD16(&Bs[c*512], &WoT[(size_t)(n0 + grow)*D_ + k0 + slot*8]);
        }
        asm volatile("s_waitcnt vmcnt(0)" ::: "memory");
        __syncthreads();
#pragma unroll
        for (int ks = 0; ks < 4; ++ks) {
            const int br = wid*16 + (lane & 15);
            const int bbyte = br*256 + ks*64 + (lane>>4)*16;
            const bf16x8 b = *reinterpret_cast<const bf16x8*>(
                reinterpret_cast<const char*>(Bs) + SWZR(bbyte, br));
#pragma unroll
            for (int i = 0; i < 2; ++i) {
                const int ar = i*16 + (lane & 15);
                const int abyte = ar*256 + ks*64 + (lane>>4)*16;
                const bf16x8 a = *reinterpret_cast<const bf16x8*>(
                    reinterpret_cast<const char*>(As) + SWZR(abyte, ar));
                acc[i] = __builtin_amdgcn_mfma_f32_16x16x32_bf16(a, b, acc[i], 0, 0, 0);
            }
        }
        __syncthreads();
    }
#pragma unroll
    for (int i = 0; i < 2; ++i)
#pragma unroll
        for (int r = 0; r < 4; ++r) {
            const int m = m0 + i*16 + (lane>>4)*4 + r;
            const int n = n0 + wid*16 + (lane & 15);
            out[(size_t)m*D_ + n] = acc[i][r] + bo[n];
        }
}

// ---------------------------------------------------------------------------
extern "C" void kernel_launch(void* const* d_in, const int* in_sizes, int n_in,
                              void* d_out, int out_size, void* d_ws, size_t ws_size,
                              hipStream_t stream)
{
    const float* x  = (const float*)d_in[0];
    const float* Wq = (const float*)d_in[1];
    const float* bq = (const float*)d_in[2];
    const float* Wk = (const float*)d_in[3];
    const float* bk = (const float*)d_in[4];
    const float* Wv = (const float*)d_in[5];
    const float* bv = (const float*)d_in[6];
    const float* Wo = (const float*)d_in[7];
    const float* bo = (const float*)d_in[8];
    const float* gc = (const float*)d_in[9];
    const float* gs = (const float*)d_in[10];
    const float* gw = (const float*)d_in[11];
    const float* tw = (const float*)d_in[12];

    short* xb    = (short*)d_ws;                      // 1,048,576 bf16
    short* WqkvT = xb + 1048576;                      //   786,432 bf16
    short* WoT   = WqkvT + 786432;                    //   262,144 bf16
    short* vT    = WoT + 262144;                      // 1,048,576 bf16
    short* ctxb  = vT + 1048576;                      // 1,048,576 bf16
    float* qm    = (float*)(ctxb + 1048576);          //    81,920 f32
    float* km    = qm + 81920;                        //    81,920 f32

    float* out0 = (float*)d_out;                      // (B,S,D)
    float* attn = out0 + (size_t)B_*S_*D_;            // (B,H,S,S)

    convert_fused<<<512, 256, 0, stream>>>(x, Wq, Wk, Wv, Wo, xb, WqkvT, WoT);
    qkv_mfma<<<dim3(NROW/64, 1536/64), 256, 0, stream>>>(
        xb, WqkvT, bq, bk, bv, gc, gs, gw, qm, km, vT);
    scores_av<<<dim3(S_/32, B_*H_), 256, 0, stream>>>(qm, km, tw, vT, attn, ctxb);
    out_mfma<<<dim3(NROW/32, D_/64), 256, 0, stream>>>(ctxb, WoT, bo, out0);
}